// Round 4
// baseline (626.295 us; speedup 1.0000x reference)
//
#include <hip/hip_runtime.h>

#define IMG_H 512
#define IMG_W 512
#define NCH 3
#define NB 32
#define RSTRIP 8
#define NSTRIP (IMG_H / RSTRIP)   // 64 strips per channel-image

// One wave (64 lanes) owns a full 512-wide strip of RSTRIP output rows.
// Each lane owns 8 contiguous columns. Vertical 7-tap window kept as 5 running
// column-sums (x,y,xx,yy,xy); slid by adding row r+4 and re-loading row r-3
// (L1/L2-warm: this wave loaded it 7 iterations earlier). Horizontal 7-tap via
// lane-neighbor shfl halos of the vertical sums. No LDS, no barriers.
__global__ __launch_bounds__(256, 4) void ssim_kernel(const float* __restrict__ x,
                                                      const float* __restrict__ y,
                                                      float* __restrict__ out)
{
    const int tid  = threadIdx.x;
    const int lane = tid & 63;
    const int wid  = (blockIdx.x << 2) + (tid >> 6);
    const int b     = wid / (NCH * NSTRIP);
    const int rem   = wid % (NCH * NSTRIP);
    const int ch    = rem / NSTRIP;
    const int strip = rem % NSTRIP;
    const int r0    = strip * RSTRIP;

    const int ibase = (b * NCH + ch) * (IMG_H * IMG_W) + lane * 8;  // < 2^25, int-safe
    const float* __restrict__ xp = x + ibase;
    const float* __restrict__ yp = y + ibase;

    float vsx[8], vsy[8], vsxx[8], vsyy[8], vsxy[8];
    #pragma unroll
    for (int i = 0; i < 8; ++i) { vsx[i]=vsy[i]=vsxx[i]=vsyy[i]=vsxy[i]=0.f; }

    // ---- prologue: accumulate rows r0-3 .. r0+3 (zero-padded outside) ----
    #pragma unroll
    for (int j = -3; j <= 3; ++j) {
        const int rr = r0 + j;            // wave-uniform -> scalar branch
        if (rr >= 0 && rr < IMG_H) {
            const int ro = rr * IMG_W;
            float xn[8], yn[8];
            *(float4*)&xn[0] = *(const float4*)(xp + ro);
            *(float4*)&xn[4] = *(const float4*)(xp + ro + 4);
            *(float4*)&yn[0] = *(const float4*)(yp + ro);
            *(float4*)&yn[4] = *(const float4*)(yp + ro + 4);
            #pragma unroll
            for (int i = 0; i < 8; ++i) {
                vsx[i] += xn[i];
                vsy[i] += yn[i];
                vsxx[i] = fmaf(xn[i], xn[i], vsxx[i]);
                vsyy[i] = fmaf(yn[i], yn[i], vsyy[i]);
                vsxy[i] = fmaf(xn[i], yn[i], vsxy[i]);
            }
        }
    }

    const float C1v = 1e-4f;
    const float C2v = 9e-4f;
    const float inv49 = 1.0f / 49.0f;
    float acc = 0.f;

    #pragma unroll
    for (int u = 0; u < RSTRIP; ++u) {
        const int r = r0 + u;
        // ---- issue slide loads early (row r+4 enters, row r-3 leaves) ----
        const bool slide = (u < RSTRIP - 1);
        const int ra = r + 4, rs = r - 3;
        float xn[8], yn[8], xo[8], yo[8];
        #pragma unroll
        for (int i = 0; i < 8; ++i) { xn[i]=yn[i]=xo[i]=yo[i]=0.f; }
        if (slide && ra < IMG_H) {
            const int ro = ra * IMG_W;
            *(float4*)&xn[0] = *(const float4*)(xp + ro);
            *(float4*)&xn[4] = *(const float4*)(xp + ro + 4);
            *(float4*)&yn[0] = *(const float4*)(yp + ro);
            *(float4*)&yn[4] = *(const float4*)(yp + ro + 4);
        }
        if (slide && rs >= 0) {
            const int ro = rs * IMG_W;
            *(float4*)&xo[0] = *(const float4*)(xp + ro);
            *(float4*)&xo[4] = *(const float4*)(xp + ro + 4);
            *(float4*)&yo[0] = *(const float4*)(yp + ro);
            *(float4*)&yo[4] = *(const float4*)(yp + ro + 4);
        }

        // ---- halo exchange of vertical sums with neighbor lanes ----
        float hlx[3], hly[3], hlxx[3], hlyy[3], hlxy[3];
        float hrx[3], hry[3], hrxx[3], hryy[3], hrxy[3];
        #pragma unroll
        for (int k = 0; k < 3; ++k) {
            float t;
            t = __shfl_up(vsx[5+k], 1, 64);  hlx[k]  = (lane == 0)  ? 0.f : t;
            t = __shfl_up(vsy[5+k], 1, 64);  hly[k]  = (lane == 0)  ? 0.f : t;
            t = __shfl_up(vsxx[5+k], 1, 64); hlxx[k] = (lane == 0)  ? 0.f : t;
            t = __shfl_up(vsyy[5+k], 1, 64); hlyy[k] = (lane == 0)  ? 0.f : t;
            t = __shfl_up(vsxy[5+k], 1, 64); hlxy[k] = (lane == 0)  ? 0.f : t;
            t = __shfl_down(vsx[k], 1, 64);  hrx[k]  = (lane == 63) ? 0.f : t;
            t = __shfl_down(vsy[k], 1, 64);  hry[k]  = (lane == 63) ? 0.f : t;
            t = __shfl_down(vsxx[k], 1, 64); hrxx[k] = (lane == 63) ? 0.f : t;
            t = __shfl_down(vsyy[k], 1, 64); hryy[k] = (lane == 63) ? 0.f : t;
            t = __shfl_down(vsxy[k], 1, 64); hrxy[k] = (lane == 63) ? 0.f : t;
        }

        // ---- horizontal sliding 7-tap + SSIM per column ----
        float hx  = hlx[0]+hlx[1]+hlx[2]+vsx[0]+vsx[1]+vsx[2]+vsx[3];
        float hy  = hly[0]+hly[1]+hly[2]+vsy[0]+vsy[1]+vsy[2]+vsy[3];
        float hxx = hlxx[0]+hlxx[1]+hlxx[2]+vsxx[0]+vsxx[1]+vsxx[2]+vsxx[3];
        float hyy = hlyy[0]+hlyy[1]+hlyy[2]+vsyy[0]+vsyy[1]+vsyy[2]+vsyy[3];
        float hxy = hlxy[0]+hlxy[1]+hlxy[2]+vsxy[0]+vsxy[1]+vsxy[2]+vsxy[3];
        #pragma unroll
        for (int i = 0; i < 8; ++i) {
            if (i > 0) {
                const float ax  = (i+6 < 11) ? vsx[i+3]  : hrx[i-5];
                const float ay  = (i+6 < 11) ? vsy[i+3]  : hry[i-5];
                const float axx = (i+6 < 11) ? vsxx[i+3] : hrxx[i-5];
                const float ayy = (i+6 < 11) ? vsyy[i+3] : hryy[i-5];
                const float axy = (i+6 < 11) ? vsxy[i+3] : hrxy[i-5];
                const float sx_ = (i-1 < 3) ? hlx[i-1]  : vsx[i-4];
                const float sy_ = (i-1 < 3) ? hly[i-1]  : vsy[i-4];
                const float sxx_= (i-1 < 3) ? hlxx[i-1] : vsxx[i-4];
                const float syy_= (i-1 < 3) ? hlyy[i-1] : vsyy[i-4];
                const float sxy_= (i-1 < 3) ? hlxy[i-1] : vsxy[i-4];
                hx += ax - sx_;  hy += ay - sy_;
                hxx += axx - sxx_; hyy += ayy - syy_; hxy += axy - sxy_;
            }
            const float mx = hx * inv49, my = hy * inv49;
            const float sxx = fmaf(-mx, mx, hxx * inv49);
            const float syy = fmaf(-my, my, hyy * inv49);
            const float sxy = fmaf(-mx, my, hxy * inv49);
            const float num = fmaf(2.f * mx, my, C1v) * fmaf(2.f, sxy, C2v);
            const float den = fmaf(mx, mx, fmaf(my, my, C1v)) * (sxx + syy + C2v);
            acc += num * __builtin_amdgcn_rcpf(den + 1e-12f);
        }

        // ---- vertical window update (consumes this iter's loads) ----
        if (slide) {
            #pragma unroll
            for (int i = 0; i < 8; ++i) {
                const float dx = xn[i] - xo[i], sx = xn[i] + xo[i];
                const float dy = yn[i] - yo[i], sy = yn[i] + yo[i];
                vsx[i] += dx;
                vsy[i] += dy;
                vsxx[i] = fmaf(dx, sx, vsxx[i]);
                vsyy[i] = fmaf(dy, sy, vsyy[i]);
                vsxy[i] = fmaf(xn[i], yn[i], vsxy[i] - xo[i] * yo[i]);
            }
        }
    }

    // ---- wave reduction + one atomic per wave ----
    #pragma unroll
    for (int off = 32; off; off >>= 1) acc += __shfl_down(acc, off, 64);
    if (lane == 0)
        atomicAdd(&out[b], acc * (1.0f / ((float)NCH * IMG_H * IMG_W)));
}

extern "C" void kernel_launch(void* const* d_in, const int* in_sizes, int n_in,
                              void* d_out, int out_size, void* d_ws, size_t ws_size,
                              hipStream_t stream) {
    const float* x = (const float*)d_in[0];
    const float* y = (const float*)d_in[1];
    float* out = (float*)d_out;
    hipMemsetAsync(out, 0, sizeof(float) * NB, stream);
    const int nwaves = NB * NCH * NSTRIP;       // 6144
    ssim_kernel<<<nwaves / 4, 256, 0, stream>>>(x, y, out);
}

// Round 5
// 262.912 us; speedup vs baseline: 2.3821x; 2.3821x over previous
//
#include <hip/hip_runtime.h>

#define IMG_H 512
#define IMG_W 512
#define NCH 3
#define NB 32
#define RSTRIP 8
#define NSTRIP (IMG_H / RSTRIP)   // 64 strips per channel-image

// One wave (64 lanes) owns a full 512-wide strip of RSTRIP output rows.
// Each lane owns 8 contiguous columns. Vertical 7-tap window kept as 5 running
// column-sums (x,y,xx,yy,xy); slid by adding row r+4 and re-loading row r-3.
// Horizontal 7-tap via lane-neighbor shfl halos of the vertical sums.
// No LDS tiles, no barriers. NOTE: needs ~90-120 VGPRs — do NOT add a
// min-waves launch_bounds arg (R4: capped to 64 VGPR -> 1.4 GB scratch spill).
__global__ __launch_bounds__(256) void ssim_kernel(const float* __restrict__ x,
                                                   const float* __restrict__ y,
                                                   float* __restrict__ out)
{
    const int tid  = threadIdx.x;
    const int lane = tid & 63;
    const int wid  = (blockIdx.x << 2) + (tid >> 6);
    const int b     = wid / (NCH * NSTRIP);
    const int rem   = wid % (NCH * NSTRIP);
    const int ch    = rem / NSTRIP;
    const int strip = rem % NSTRIP;
    const int r0    = strip * RSTRIP;

    const int ibase = (b * NCH + ch) * (IMG_H * IMG_W) + lane * 8;  // < 2^25, int-safe
    const float* __restrict__ xp = x + ibase;
    const float* __restrict__ yp = y + ibase;

    float vsx[8], vsy[8], vsxx[8], vsyy[8], vsxy[8];
    #pragma unroll
    for (int i = 0; i < 8; ++i) { vsx[i]=vsy[i]=vsxx[i]=vsyy[i]=vsxy[i]=0.f; }

    // ---- prologue: accumulate rows r0-3 .. r0+3 (zero-padded outside) ----
    #pragma unroll
    for (int j = -3; j <= 3; ++j) {
        const int rr = r0 + j;            // wave-uniform -> scalar branch
        if (rr >= 0 && rr < IMG_H) {
            const int ro = rr * IMG_W;
            float xn[8], yn[8];
            *(float4*)&xn[0] = *(const float4*)(xp + ro);
            *(float4*)&xn[4] = *(const float4*)(xp + ro + 4);
            *(float4*)&yn[0] = *(const float4*)(yp + ro);
            *(float4*)&yn[4] = *(const float4*)(yp + ro + 4);
            #pragma unroll
            for (int i = 0; i < 8; ++i) {
                vsx[i] += xn[i];
                vsy[i] += yn[i];
                vsxx[i] = fmaf(xn[i], xn[i], vsxx[i]);
                vsyy[i] = fmaf(yn[i], yn[i], vsyy[i]);
                vsxy[i] = fmaf(xn[i], yn[i], vsxy[i]);
            }
        }
    }

    const float C1v = 1e-4f;
    const float C2v = 9e-4f;
    const float inv49 = 1.0f / 49.0f;
    float acc = 0.f;

    #pragma unroll 2
    for (int u = 0; u < RSTRIP; ++u) {
        const int r = r0 + u;
        // ---- issue slide loads early (row r+4 enters, row r-3 leaves) ----
        const bool slide = (u < RSTRIP - 1);
        const int ra = r + 4, rs = r - 3;
        float xn[8], yn[8], xo[8], yo[8];
        #pragma unroll
        for (int i = 0; i < 8; ++i) { xn[i]=yn[i]=xo[i]=yo[i]=0.f; }
        if (slide && ra < IMG_H) {
            const int ro = ra * IMG_W;
            *(float4*)&xn[0] = *(const float4*)(xp + ro);
            *(float4*)&xn[4] = *(const float4*)(xp + ro + 4);
            *(float4*)&yn[0] = *(const float4*)(yp + ro);
            *(float4*)&yn[4] = *(const float4*)(yp + ro + 4);
        }
        if (slide && rs >= 0) {
            const int ro = rs * IMG_W;
            *(float4*)&xo[0] = *(const float4*)(xp + ro);
            *(float4*)&xo[4] = *(const float4*)(xp + ro + 4);
            *(float4*)&yo[0] = *(const float4*)(yp + ro);
            *(float4*)&yo[4] = *(const float4*)(yp + ro + 4);
        }

        // ---- halo exchange of vertical sums with neighbor lanes ----
        float hlx[3], hly[3], hlxx[3], hlyy[3], hlxy[3];
        float hrx[3], hry[3], hrxx[3], hryy[3], hrxy[3];
        #pragma unroll
        for (int k = 0; k < 3; ++k) {
            float t;
            t = __shfl_up(vsx[5+k], 1, 64);  hlx[k]  = (lane == 0)  ? 0.f : t;
            t = __shfl_up(vsy[5+k], 1, 64);  hly[k]  = (lane == 0)  ? 0.f : t;
            t = __shfl_up(vsxx[5+k], 1, 64); hlxx[k] = (lane == 0)  ? 0.f : t;
            t = __shfl_up(vsyy[5+k], 1, 64); hlyy[k] = (lane == 0)  ? 0.f : t;
            t = __shfl_up(vsxy[5+k], 1, 64); hlxy[k] = (lane == 0)  ? 0.f : t;
            t = __shfl_down(vsx[k], 1, 64);  hrx[k]  = (lane == 63) ? 0.f : t;
            t = __shfl_down(vsy[k], 1, 64);  hry[k]  = (lane == 63) ? 0.f : t;
            t = __shfl_down(vsxx[k], 1, 64); hrxx[k] = (lane == 63) ? 0.f : t;
            t = __shfl_down(vsyy[k], 1, 64); hryy[k] = (lane == 63) ? 0.f : t;
            t = __shfl_down(vsxy[k], 1, 64); hrxy[k] = (lane == 63) ? 0.f : t;
        }

        // ---- horizontal sliding 7-tap + SSIM per column ----
        float hx  = hlx[0]+hlx[1]+hlx[2]+vsx[0]+vsx[1]+vsx[2]+vsx[3];
        float hy  = hly[0]+hly[1]+hly[2]+vsy[0]+vsy[1]+vsy[2]+vsy[3];
        float hxx = hlxx[0]+hlxx[1]+hlxx[2]+vsxx[0]+vsxx[1]+vsxx[2]+vsxx[3];
        float hyy = hlyy[0]+hlyy[1]+hlyy[2]+vsyy[0]+vsyy[1]+vsyy[2]+vsyy[3];
        float hxy = hlxy[0]+hlxy[1]+hlxy[2]+vsxy[0]+vsxy[1]+vsxy[2]+vsxy[3];
        #pragma unroll
        for (int i = 0; i < 8; ++i) {
            if (i > 0) {
                const float ax  = (i+6 < 11) ? vsx[i+3]  : hrx[i-5];
                const float ay  = (i+6 < 11) ? vsy[i+3]  : hry[i-5];
                const float axx = (i+6 < 11) ? vsxx[i+3] : hrxx[i-5];
                const float ayy = (i+6 < 11) ? vsyy[i+3] : hryy[i-5];
                const float axy = (i+6 < 11) ? vsxy[i+3] : hrxy[i-5];
                const float sx_ = (i-1 < 3) ? hlx[i-1]  : vsx[i-4];
                const float sy_ = (i-1 < 3) ? hly[i-1]  : vsy[i-4];
                const float sxx_= (i-1 < 3) ? hlxx[i-1] : vsxx[i-4];
                const float syy_= (i-1 < 3) ? hlyy[i-1] : vsyy[i-4];
                const float sxy_= (i-1 < 3) ? hlxy[i-1] : vsxy[i-4];
                hx += ax - sx_;  hy += ay - sy_;
                hxx += axx - sxx_; hyy += ayy - syy_; hxy += axy - sxy_;
            }
            const float mx = hx * inv49, my = hy * inv49;
            const float sxx = fmaf(-mx, mx, hxx * inv49);
            const float syy = fmaf(-my, my, hyy * inv49);
            const float sxy = fmaf(-mx, my, hxy * inv49);
            const float num = fmaf(2.f * mx, my, C1v) * fmaf(2.f, sxy, C2v);
            const float den = fmaf(mx, mx, fmaf(my, my, C1v)) * (sxx + syy + C2v);
            acc += num * __builtin_amdgcn_rcpf(den + 1e-12f);
        }

        // ---- vertical window update (consumes this iter's loads) ----
        if (slide) {
            #pragma unroll
            for (int i = 0; i < 8; ++i) {
                const float dx = xn[i] - xo[i], sx = xn[i] + xo[i];
                const float dy = yn[i] - yo[i], sy = yn[i] + yo[i];
                vsx[i] += dx;
                vsy[i] += dy;
                vsxx[i] = fmaf(dx, sx, vsxx[i]);
                vsyy[i] = fmaf(dy, sy, vsyy[i]);
                vsxy[i] = fmaf(xn[i], yn[i], vsxy[i] - xo[i] * yo[i]);
            }
        }
    }

    // ---- wave reduction + one atomic per wave ----
    #pragma unroll
    for (int off = 32; off; off >>= 1) acc += __shfl_down(acc, off, 64);
    if (lane == 0)
        atomicAdd(&out[b], acc * (1.0f / ((float)NCH * IMG_H * IMG_W)));
}

extern "C" void kernel_launch(void* const* d_in, const int* in_sizes, int n_in,
                              void* d_out, int out_size, void* d_ws, size_t ws_size,
                              hipStream_t stream) {
    const float* x = (const float*)d_in[0];
    const float* y = (const float*)d_in[1];
    float* out = (float*)d_out;
    hipMemsetAsync(out, 0, sizeof(float) * NB, stream);
    const int nwaves = NB * NCH * NSTRIP;       // 6144
    ssim_kernel<<<nwaves / 4, 256, 0, stream>>>(x, y, out);
}